// Round 6
// baseline (96.581 us; speedup 1.0000x reference)
//
#include <hip/hip_runtime.h>
#include <math.h>

// ---------------- constants (fp64, folded at compile time) ----------------
#define PI_D      3.14159265358979323846
#define K_D       (1.0 / 44100.0)
#define MAX_OM_D  (10000.0 * 2.0 * PI_D)
#define LN10      2.30258509299404568402
#define ALPHA_D   (3.0 * LN10 / 6.0)                 // DOMSQ == OM2^2 -> 3*ln10/6
#define OM2_D     (2.0 * PI_D * 500.0)
#define BETA_D    (3.0 * LN10 / (OM2_D * OM2_D) * (1.0 / 2.0 - 1.0 / 6.0))
#define LOG2E_D   1.44269504088896340736
#define INV2PI_D  0.15915494309189533577

#define NMODES  6400
#define TPB     256
#define NS      6                 // samples per thread (stride TPB)
#define TILE    (TPB * NS)        // 1536 samples per time-tile
#define NCHUNK  32
#define CHUNK_M (NMODES / NCHUNK) // 200 modes per block

#if defined(__has_builtin) && __has_builtin(__builtin_amdgcn_sinf)
#define SIN_REV(x) __builtin_amdgcn_sinf(x)        // v_sin_f32: revolutions
#else
#define SIN_REV(x) __sinf((x) * 6.28318530717958647692f)
#endif
#if defined(__has_builtin) && __has_builtin(__builtin_amdgcn_cosf)
#define COS_REV(x) __builtin_amdgcn_cosf(x)
#else
#define COS_REV(x) __cosf((x) * 6.28318530717958647692f)
#endif
#if defined(__has_builtin) && __has_builtin(__builtin_amdgcn_exp2f)
#define EXP2F(x) __builtin_amdgcn_exp2f(x)
#else
#define EXP2F(x) exp2f(x)
#endif
#if defined(__has_builtin) && __has_builtin(__builtin_amdgcn_fractf)
#define FRACTF(x) __builtin_amdgcn_fractf(x)
#else
#define FRACTF(x) ((x) - floorf(x))
#endif

__device__ inline double softplus_fast(double x) {
    float xf = (float)x;
    float r = (xf > 0.0f) ? xf + log1pf(__expf(-xf)) : log1pf(__expf(xf));
    return (double)r;
}
__device__ inline float cosrev_d(double x) { return COS_REV((float)(x - floor(x))); }
__device__ inline float sinrev_d(double x) { return SIN_REV((float)(x - floor(x))); }
__device__ inline float sigmoid_f(double x) { return 1.0f / (1.0f + __expf((float)(-x))); }

// ------- kernel 1: self-staging synth -> private partial plane per chunk -------
// partial layout: [(chunk*gx + tile)*TILE + loc]; every slot written (no pre-zero).
__global__ __launch_bounds__(TPB) void synth_kernel(
        const float* __restrict__ mu_raw,  const float* __restrict__ Dmu_raw,
        const float* __restrict__ Tmu_raw, const float* __restrict__ Ly_raw,
        const float* __restrict__ xo_raw,  const float* __restrict__ yo_raw,
        float* __restrict__ partial, int T, int gx) {
    __shared__ float4 sA[CHUNK_M];   // {base, cb, c1, c2}
    __shared__ float4 sB[CHUNK_M];   // {ph32, base2, cb2, dec2}
    __shared__ int    s_cnt;

    const int tile  = blockIdx.x;
    const int chunk = blockIdx.y;
    const int t0    = tile * TILE;
    const int tid   = threadIdx.x;

    if (tid == 0) s_cnt = 0;
    __syncthreads();

    // ---- staging: compute this block's 200 modes' params (fp64 arith, fp32 trans) ----
    if (tid < CHUNK_M) {
        const int i = chunk * CHUNK_M + tid;
        double mu  = softplus_fast((double)mu_raw[0])  + 1e-4;
        double Dmu = softplus_fast((double)Dmu_raw[0]) + 1e-4;
        double Tmu = softplus_fast((double)Tmu_raw[0]) + 1e-4;
        double Ly  = 1.1 + (4.0 - 1.1) * (((double)tanhf(Ly_raw[0]) + 1.0) * 0.5);
        double xo  = 0.49 + 0.51 * (((double)tanhf(xo_raw[0]) + 1.0) * 0.5);  // LX=1
        double yoL = 0.51 + 0.49 * (((double)tanhf(yo_raw[0]) + 1.0) * 0.5);  // yo/Ly

        int m = i / 80 + 1, n = i % 80 + 1;
        double md = (double)m, nd = (double)n;
        double a  = md * PI_D;
        double b  = nd * PI_D / Ly;
        double g1 = a * a + b * b;
        double omsq  = Tmu * g1 + Dmu * g1 * g1;
        double omega = sqrt(omsq > 0.0 ? omsq : 0.0);

        float valid = sigmoid_f((MAX_OM_D - omega) * 0.01) *
                      sigmoid_f((omega - 40.0 * PI_D) * 0.01);
        float in_w  = cosrev_d(0.1675 * md) * cosrev_d(0.2335 * nd);   // yi/Ly = 0.467
        float out_w = cosrev_d(0.5 * xo * md) * cosrev_d(0.5 * yoL * nd);

        double sigma = ALPHA_D + BETA_D * omega * omega;
        double ph64  = omega * K_D * INV2PI_D;          // revolutions per sample
        float envK = __expf((float)(-sigma * K_D));
        float P    = out_w * in_w * (float)(K_D * K_D / (0.25 * mu * Ly)) * envK * valid;
        float coef = P / (sinrev_d(ph64) + 1e-8f);
        float dec2 = (float)(-sigma * K_D * LOG2E_D);   // env = 2^(dec2*t)

        float cb = coef * EXP2F(dec2 * (float)t0);      // coef*env(t0); 0 when dead/gated
        if (cb != 0.0f) {
            // stride-256 recurrence constants (fp64 phase reduction)
            float r256 = EXP2F(dec2 * 256.0f);          // rho^256
            double p256 = ph64 * 256.0;
            float d256 = (float)(p256 - floor(p256));
            float c1 = 2.0f * r256 * COS_REV(d256);
            float c2 = r256 * r256;
            double bd = ph64 * (double)(t0 + 1);        // revs at loc=0 (sine arg n+1)
            float base  = (float)(bd - floor(bd));
            float base2 = base + d256;                  // second-seed base
            int idx = atomicAdd(&s_cnt, 1);
            sA[idx] = make_float4(base, cb, c1, c2);
            sB[idx] = make_float4((float)ph64, base2, cb * r256, dec2);
        }
    }
    __syncthreads();
    const int n_act = s_cnt;

    // ---- synth: seed 2 samples, recur NS-2 via y2 = c1*y1 - c2*y0 ----
    float acc[NS];
    #pragma unroll
    for (int i = 0; i < NS; ++i) acc[i] = 0.0f;
    const float tidf = (float)tid;

    for (int j = 0; j < n_act; ++j) {
        float4 a = sA[j];                        // broadcast ds_read_b128 x2
        float4 b = sB[j];
        float s0 = SIN_REV(FRACTF(fmaf(b.x, tidf, a.x)));   // |arg| < 60 revs: fp32 ok
        float s1 = SIN_REV(FRACTF(fmaf(b.x, tidf, b.y)));
        float e  = EXP2F(b.w * tidf);
        float y0 = a.y * e * s0;                 // cb  * env(tid) * sin
        float y1 = b.z * e * s1;                 // cb2 * env(tid) * sin
        acc[0] += y0;
        acc[1] += y1;
        #pragma unroll
        for (int i = 2; i < NS; ++i) {
            float y2 = fmaf(a.z, y1, -(a.w * y0));
            acc[i] += y2;
            y0 = y1; y1 = y2;
        }
    }
    // plain coalesced stores into this chunk's private plane (every slot written)
    float* dst = partial + ((size_t)(chunk * gx + tile)) * TILE + tid;
    #pragma unroll
    for (int i = 0; i < NS; ++i)
        dst[TPB * i] = acc[i];
}

// ------- kernel 2: sum 32 planes + first-difference + per-block max (plain store) -------
__global__ __launch_bounds__(TPB) void diff_max_kernel(const float* __restrict__ partial,
                                                       float* __restrict__ out,
                                                       float* __restrict__ gmax_arr,
                                                       int T, int gx) {
    __shared__ float sh[TPB + 1];
    __shared__ float s_red[TPB / 64];
    const int tid = threadIdx.x;
    const int t   = blockIdx.x * TPB + tid;
    const int stride = gx * TILE;               // plane size in floats

    float s = 0.0f;
    if (t < T) {
        const float* base = partial + (t / TILE) * TILE + (t % TILE);
        #pragma unroll
        for (int c = 0; c < NCHUNK; ++c) s += base[c * stride];
    }
    sh[tid + 1] = s;
    if (tid == 0) {
        float sp = 0.0f;
        int tp = blockIdx.x * TPB - 1;
        if (tp >= 0) {
            const float* base = partial + (tp / TILE) * TILE + (tp % TILE);
            #pragma unroll
            for (int c = 0; c < NCHUNK; ++c) sp += base[c * stride];
        }
        sh[0] = sp;
    }
    __syncthreads();

    float v = 0.0f;
    if (t < T) {
        v = (s - sh[tid]) * 44100.0f;           // ir = diff / K
        out[t] = v;
    }
    float lmax = fabsf(v);
    for (int o = 32; o > 0; o >>= 1)
        lmax = fmaxf(lmax, __shfl_down(lmax, o, 64));
    if ((tid & 63) == 0) s_red[tid >> 6] = lmax;
    __syncthreads();
    if (tid == 0)
        gmax_arr[blockIdx.x] = fmaxf(fmaxf(s_red[0], s_red[1]),
                                     fmaxf(s_red[2], s_red[3]));
}

// ------- kernel 3: reduce block maxes + normalize -------
__global__ __launch_bounds__(TPB) void normalize_kernel(float* __restrict__ out,
                                                        const float* __restrict__ gmax_arr,
                                                        int T, int nmax) {
    __shared__ float s_red[TPB / 64];
    const int tid = threadIdx.x;
    float m = (tid < nmax) ? gmax_arr[tid] : 0.0f;   // nmax <= TPB
    for (int o = 32; o > 0; o >>= 1)
        m = fmaxf(m, __shfl_down(m, o, 64));
    if ((tid & 63) == 0) s_red[tid >> 6] = m;
    __syncthreads();
    float gm = fmaxf(fmaxf(s_red[0], s_red[1]), fmaxf(s_red[2], s_red[3]));
    const float inv = 1.0f / (gm + 1e-8f);
    int t = blockIdx.x * TPB + tid;
    if (t < T) out[t] *= inv;
}

extern "C" void kernel_launch(void* const* d_in, const int* in_sizes, int n_in,
                              void* d_out, int out_size, void* d_ws, size_t ws_size,
                              hipStream_t stream) {
    const float* mu_raw  = (const float*)d_in[0];
    const float* Dmu_raw = (const float*)d_in[1];
    const float* Tmu_raw = (const float*)d_in[2];
    const float* Ly_raw  = (const float*)d_in[3];
    const float* xo_raw  = (const float*)d_in[4];
    const float* yo_raw  = (const float*)d_in[5];
    float* out = (float*)d_out;
    int T = out_size;
    if (T <= 0) return;

    int gx  = (T + TILE - 1) / TILE;          // time tiles (15 for T=22050)
    int nb2 = (T + TPB - 1) / TPB;            // 87 blocks; must be <= TPB for normalize

    // workspace: partial planes + block-max array (no init required anywhere)
    char* ws = (char*)d_ws;
    float* partial  = (float*)(ws + 0);                              // 32*gx*TILE*4 B
    float* gmax_arr = (float*)(ws + (size_t)NCHUNK * gx * TILE * 4); // nb2*4 B

    dim3 grid(gx, NCHUNK);
    synth_kernel<<<grid, TPB, 0, stream>>>(
        mu_raw, Dmu_raw, Tmu_raw, Ly_raw, xo_raw, yo_raw, partial, T, gx);

    diff_max_kernel<<<nb2, TPB, 0, stream>>>(partial, out, gmax_arr, T, gx);
    normalize_kernel<<<nb2, TPB, 0, stream>>>(out, gmax_arr, T, nb2);
}